// Round 10
// baseline (208.243 us; speedup 1.0000x reference)
//
#include <hip/hip_runtime.h>
#include <hip/hip_bf16.h>

// Problem constants: B=4, L=2048, H=8, D=64, SAMPLE_K=N_TOP=40
#define BB 4
#define LL 2048
#define HH 8
#define DD 64
#define SK 40
#define NT 40
#define CH 256              // keys per attn chunk
#define NCH (LL / CH)       // 8 chunks per (b,h)
#define QH 20               // queries per attn block (40 split in 2)

typedef float f4 __attribute__((ext_vector_type(4)));

// ---------------------------------------------------------------------------
// Kernel 1: M[bh][l] = max_s(q . k_{idx[l,s]}) - (sum_s q . k_{idx[l,s]}) / L
//
// Round 23 (fixes round-22 consume-count bug: phase 0 consumed only 32/40
// samples and phase-1 prologue overwrote 8 in-flight registers -> absmax
// 0.29). Same half-row time-phasing idea, now as ONE 80-step rolling
// pipeline. Head h uses only floats [h*64,+64): first 1KB of a row serves
// heads 0-3, second 1KB heads 4-7. Steps 0-39 gather first halves (per-batch
// live set 2.1MB -> fits 4MB XCD L2), steps 40-79 second halves. Sample j
// lives in register j&15; prologue issues 0-15; steps j=0..63 do
// {CO(j)@vmcnt(15); IS(j+16)}; tail j=64..79 drains vmcnt(15..0). Every
// sample consumed exactly once; each register re-issued only after consume.
// Per sample: one dwordx4/lane (floats [lane*4,+4) of the half = head
// (lane>>4)+4*phase, dims 4*(lane&15)..), 4 FMA, 4 shfl (16-lane groups).
// Q loads nontemporal (single-use, don't evict K). No LDS, no barriers.
// ---------------------------------------------------------------------------
__global__ __launch_bounds__(256, 4) void compute_m_kernel(
        const float* __restrict__ Q, const float* __restrict__ K,
        const int* __restrict__ idx, float* __restrict__ M) {
    int blk = blockIdx.x;
    int x = blk & 7, g = blk >> 3;
    int b = x >> 1;                    // 2 XCDs per batch
    int lg = (g << 1) | (x & 1);       // l-group [0,512)
    int t = threadIdx.x;
    int lane = t & 63, w = t >> 6;
    int l = lg * 4 + w;                // this wave's l

    // Q fragments (identity map with K halves), nontemporal single-use
    const f4* q0p = (const f4*)(Q + ((size_t)b * LL + l) * 512 + lane * 4);
    const f4* q1p = (const f4*)(Q + ((size_t)b * LL + l) * 512 + 256 + lane * 4);
    f4 qf0 = __builtin_nontemporal_load(q0p);
    f4 qf1 = __builtin_nontemporal_load(q1p);

    // idx row: coalesced read by lanes 0..39, broadcast via readlane
    int myidx = 0;
    if (lane < SK) myidx = idx[(size_t)l * SK + lane];

    const float* Kb8 = K + (size_t)b * LL * 512;
    int voff0 = lane * 16;             // byte offset of lane's 16B in half 0
    int voff1 = lane * 16 + 1024;      // ... in half 1

    // Drain compiler-tracked loads (Q, idx) before the asm pipeline.
    asm volatile("" : "+v"(qf0), "+v"(qf1));

    f4 R0, R1, R2, R3, R4, R5, R6, R7, R8, R9, R10, R11, R12, R13, R14, R15;

    #define PTRK(k) (Kb8 + (size_t)__builtin_amdgcn_readlane(myidx, (k)) * 512)
    #define IS(RV, k, VO)                                                       \
        asm volatile("global_load_dwordx4 %0, %1, %2"                           \
                     : "=&v"(RV) : "v"(VO), "s"(PTRK(k)))

    float mx0 = -INFINITY, sm0 = 0.0f, mx1 = -INFINITY, sm1 = 0.0f;

    #define CO(RV, QF, MX, SM, WAIT) do {                                       \
        asm volatile(WAIT : "+v"(RV));                                          \
        float p = QF.x*RV.x + QF.y*RV.y + QF.z*RV.z + QF.w*RV.w;                \
        p += __shfl_xor(p, 1, 64);                                              \
        p += __shfl_xor(p, 2, 64);                                              \
        p += __shfl_xor(p, 4, 64);                                              \
        p += __shfl_xor(p, 8, 64);                                              \
        MX = fmaxf(MX, p);                                                      \
        SM += p;                                                                \
    } while (0)

    // prologue: phase-0 samples 0..15
    IS(R0,  0, voff0); IS(R1,  1, voff0); IS(R2,  2, voff0); IS(R3,  3, voff0);
    IS(R4,  4, voff0); IS(R5,  5, voff0); IS(R6,  6, voff0); IS(R7,  7, voff0);
    IS(R8,  8, voff0); IS(R9,  9, voff0); IS(R10, 10, voff0); IS(R11, 11, voff0);
    IS(R12, 12, voff0); IS(R13, 13, voff0); IS(R14, 14, voff0); IS(R15, 15, voff0);
    // block A (j=0..15): consume ph0 0-15, issue ph0 16-31
    CO(R0,  qf0, mx0, sm0, "s_waitcnt vmcnt(15)"); IS(R0,  16, voff0);
    CO(R1,  qf0, mx0, sm0, "s_waitcnt vmcnt(15)"); IS(R1,  17, voff0);
    CO(R2,  qf0, mx0, sm0, "s_waitcnt vmcnt(15)"); IS(R2,  18, voff0);
    CO(R3,  qf0, mx0, sm0, "s_waitcnt vmcnt(15)"); IS(R3,  19, voff0);
    CO(R4,  qf0, mx0, sm0, "s_waitcnt vmcnt(15)"); IS(R4,  20, voff0);
    CO(R5,  qf0, mx0, sm0, "s_waitcnt vmcnt(15)"); IS(R5,  21, voff0);
    CO(R6,  qf0, mx0, sm0, "s_waitcnt vmcnt(15)"); IS(R6,  22, voff0);
    CO(R7,  qf0, mx0, sm0, "s_waitcnt vmcnt(15)"); IS(R7,  23, voff0);
    CO(R8,  qf0, mx0, sm0, "s_waitcnt vmcnt(15)"); IS(R8,  24, voff0);
    CO(R9,  qf0, mx0, sm0, "s_waitcnt vmcnt(15)"); IS(R9,  25, voff0);
    CO(R10, qf0, mx0, sm0, "s_waitcnt vmcnt(15)"); IS(R10, 26, voff0);
    CO(R11, qf0, mx0, sm0, "s_waitcnt vmcnt(15)"); IS(R11, 27, voff0);
    CO(R12, qf0, mx0, sm0, "s_waitcnt vmcnt(15)"); IS(R12, 28, voff0);
    CO(R13, qf0, mx0, sm0, "s_waitcnt vmcnt(15)"); IS(R13, 29, voff0);
    CO(R14, qf0, mx0, sm0, "s_waitcnt vmcnt(15)"); IS(R14, 30, voff0);
    CO(R15, qf0, mx0, sm0, "s_waitcnt vmcnt(15)"); IS(R15, 31, voff0);
    // block B (j=16..23): consume ph0 16-23, issue ph0 32-39
    CO(R0,  qf0, mx0, sm0, "s_waitcnt vmcnt(15)"); IS(R0,  32, voff0);
    CO(R1,  qf0, mx0, sm0, "s_waitcnt vmcnt(15)"); IS(R1,  33, voff0);
    CO(R2,  qf0, mx0, sm0, "s_waitcnt vmcnt(15)"); IS(R2,  34, voff0);
    CO(R3,  qf0, mx0, sm0, "s_waitcnt vmcnt(15)"); IS(R3,  35, voff0);
    CO(R4,  qf0, mx0, sm0, "s_waitcnt vmcnt(15)"); IS(R4,  36, voff0);
    CO(R5,  qf0, mx0, sm0, "s_waitcnt vmcnt(15)"); IS(R5,  37, voff0);
    CO(R6,  qf0, mx0, sm0, "s_waitcnt vmcnt(15)"); IS(R6,  38, voff0);
    CO(R7,  qf0, mx0, sm0, "s_waitcnt vmcnt(15)"); IS(R7,  39, voff0);
    // block C (j=24..31): consume ph0 24-31, issue ph1 0-7
    CO(R8,  qf0, mx0, sm0, "s_waitcnt vmcnt(15)"); IS(R8,   0, voff1);
    CO(R9,  qf0, mx0, sm0, "s_waitcnt vmcnt(15)"); IS(R9,   1, voff1);
    CO(R10, qf0, mx0, sm0, "s_waitcnt vmcnt(15)"); IS(R10,  2, voff1);
    CO(R11, qf0, mx0, sm0, "s_waitcnt vmcnt(15)"); IS(R11,  3, voff1);
    CO(R12, qf0, mx0, sm0, "s_waitcnt vmcnt(15)"); IS(R12,  4, voff1);
    CO(R13, qf0, mx0, sm0, "s_waitcnt vmcnt(15)"); IS(R13,  5, voff1);
    CO(R14, qf0, mx0, sm0, "s_waitcnt vmcnt(15)"); IS(R14,  6, voff1);
    CO(R15, qf0, mx0, sm0, "s_waitcnt vmcnt(15)"); IS(R15,  7, voff1);
    // block D (j=32..39): consume ph0 32-39, issue ph1 8-15
    CO(R0,  qf0, mx0, sm0, "s_waitcnt vmcnt(15)"); IS(R0,   8, voff1);
    CO(R1,  qf0, mx0, sm0, "s_waitcnt vmcnt(15)"); IS(R1,   9, voff1);
    CO(R2,  qf0, mx0, sm0, "s_waitcnt vmcnt(15)"); IS(R2,  10, voff1);
    CO(R3,  qf0, mx0, sm0, "s_waitcnt vmcnt(15)"); IS(R3,  11, voff1);
    CO(R4,  qf0, mx0, sm0, "s_waitcnt vmcnt(15)"); IS(R4,  12, voff1);
    CO(R5,  qf0, mx0, sm0, "s_waitcnt vmcnt(15)"); IS(R5,  13, voff1);
    CO(R6,  qf0, mx0, sm0, "s_waitcnt vmcnt(15)"); IS(R6,  14, voff1);
    CO(R7,  qf0, mx0, sm0, "s_waitcnt vmcnt(15)"); IS(R7,  15, voff1);
    // block E (j=40..47): consume ph1 0-7, issue ph1 16-23
    CO(R8,  qf1, mx1, sm1, "s_waitcnt vmcnt(15)"); IS(R8,  16, voff1);
    CO(R9,  qf1, mx1, sm1, "s_waitcnt vmcnt(15)"); IS(R9,  17, voff1);
    CO(R10, qf1, mx1, sm1, "s_waitcnt vmcnt(15)"); IS(R10, 18, voff1);
    CO(R11, qf1, mx1, sm1, "s_waitcnt vmcnt(15)"); IS(R11, 19, voff1);
    CO(R12, qf1, mx1, sm1, "s_waitcnt vmcnt(15)"); IS(R12, 20, voff1);
    CO(R13, qf1, mx1, sm1, "s_waitcnt vmcnt(15)"); IS(R13, 21, voff1);
    CO(R14, qf1, mx1, sm1, "s_waitcnt vmcnt(15)"); IS(R14, 22, voff1);
    CO(R15, qf1, mx1, sm1, "s_waitcnt vmcnt(15)"); IS(R15, 23, voff1);
    // block F (j=48..63): consume ph1 8-23, issue ph1 24-39
    CO(R0,  qf1, mx1, sm1, "s_waitcnt vmcnt(15)"); IS(R0,  24, voff1);
    CO(R1,  qf1, mx1, sm1, "s_waitcnt vmcnt(15)"); IS(R1,  25, voff1);
    CO(R2,  qf1, mx1, sm1, "s_waitcnt vmcnt(15)"); IS(R2,  26, voff1);
    CO(R3,  qf1, mx1, sm1, "s_waitcnt vmcnt(15)"); IS(R3,  27, voff1);
    CO(R4,  qf1, mx1, sm1, "s_waitcnt vmcnt(15)"); IS(R4,  28, voff1);
    CO(R5,  qf1, mx1, sm1, "s_waitcnt vmcnt(15)"); IS(R5,  29, voff1);
    CO(R6,  qf1, mx1, sm1, "s_waitcnt vmcnt(15)"); IS(R6,  30, voff1);
    CO(R7,  qf1, mx1, sm1, "s_waitcnt vmcnt(15)"); IS(R7,  31, voff1);
    CO(R8,  qf1, mx1, sm1, "s_waitcnt vmcnt(15)"); IS(R8,  32, voff1);
    CO(R9,  qf1, mx1, sm1, "s_waitcnt vmcnt(15)"); IS(R9,  33, voff1);
    CO(R10, qf1, mx1, sm1, "s_waitcnt vmcnt(15)"); IS(R10, 34, voff1);
    CO(R11, qf1, mx1, sm1, "s_waitcnt vmcnt(15)"); IS(R11, 35, voff1);
    CO(R12, qf1, mx1, sm1, "s_waitcnt vmcnt(15)"); IS(R12, 36, voff1);
    CO(R13, qf1, mx1, sm1, "s_waitcnt vmcnt(15)"); IS(R13, 37, voff1);
    CO(R14, qf1, mx1, sm1, "s_waitcnt vmcnt(15)"); IS(R14, 38, voff1);
    CO(R15, qf1, mx1, sm1, "s_waitcnt vmcnt(15)"); IS(R15, 39, voff1);
    // tail (j=64..79): consume ph1 24-39, drain
    CO(R0,  qf1, mx1, sm1, "s_waitcnt vmcnt(15)");
    CO(R1,  qf1, mx1, sm1, "s_waitcnt vmcnt(14)");
    CO(R2,  qf1, mx1, sm1, "s_waitcnt vmcnt(13)");
    CO(R3,  qf1, mx1, sm1, "s_waitcnt vmcnt(12)");
    CO(R4,  qf1, mx1, sm1, "s_waitcnt vmcnt(11)");
    CO(R5,  qf1, mx1, sm1, "s_waitcnt vmcnt(10)");
    CO(R6,  qf1, mx1, sm1, "s_waitcnt vmcnt(9)");
    CO(R7,  qf1, mx1, sm1, "s_waitcnt vmcnt(8)");
    CO(R8,  qf1, mx1, sm1, "s_waitcnt vmcnt(7)");
    CO(R9,  qf1, mx1, sm1, "s_waitcnt vmcnt(6)");
    CO(R10, qf1, mx1, sm1, "s_waitcnt vmcnt(5)");
    CO(R11, qf1, mx1, sm1, "s_waitcnt vmcnt(4)");
    CO(R12, qf1, mx1, sm1, "s_waitcnt vmcnt(3)");
    CO(R13, qf1, mx1, sm1, "s_waitcnt vmcnt(2)");
    CO(R14, qf1, mx1, sm1, "s_waitcnt vmcnt(1)");
    CO(R15, qf1, mx1, sm1, "s_waitcnt vmcnt(0)");
    #undef IS
    #undef CO
    #undef PTRK

    // leader lanes 0/16/32/48: phase-0 result = head lane>>4, phase-1 = +4
    if ((lane & 15) == 0) {
        int h0 = lane >> 4;
        __builtin_nontemporal_store(mx0 - sm0 * (1.0f / (float)LL),
                                    &M[((size_t)b * HH + h0) * LL + l]);
        __builtin_nontemporal_store(mx1 - sm1 * (1.0f / (float)LL),
                                    &M[((size_t)b * HH + h0 + 4) * LL + l]);
    }
}

// ---------------------------------------------------------------------------
// Kernel 2: top-40 per (b,h), lower index wins ties. Incremental argmax.
// ---------------------------------------------------------------------------
__global__ __launch_bounds__(256) void topk_kernel(const float* __restrict__ M,
                                                   int* __restrict__ topi) {
    __shared__ unsigned long long keys[LL];   // 16 KB
    __shared__ unsigned long long wmax[4];
    __shared__ int win;
    int bh = blockIdx.x;
    int t  = threadIdx.x;
    int lane = t & 63, w = t >> 6;

    unsigned long long kmax = 0ULL;
    #pragma unroll
    for (int j = 0; j < 8; ++j) {
        int i = t + 256 * j;
        unsigned int bits = __float_as_uint(M[(size_t)bh * LL + i]);
        bits = (bits & 0x80000000u) ? ~bits : (bits | 0x80000000u);
        unsigned long long k = ((unsigned long long)bits << 11)
                             | (unsigned int)(LL - 1 - i);
        keys[i] = k;
        if (k > kmax) kmax = k;
    }
    __syncthreads();

    for (int u = 0; u < NT; ++u) {
        unsigned long long k = kmax;
        #pragma unroll
        for (int off = 32; off >= 1; off >>= 1) {
            unsigned long long o = __shfl_xor(k, off, 64);
            if (o > k) k = o;
        }
        if (lane == 0) wmax[w] = k;
        __syncthreads();
        if (t == 0) {
            unsigned long long k0 = wmax[0];
            if (wmax[1] > k0) k0 = wmax[1];
            if (wmax[2] > k0) k0 = wmax[2];
            if (wmax[3] > k0) k0 = wmax[3];
            int i = (LL - 1) - (int)(k0 & 0x7FF);
            topi[bh * NT + u] = i;
            keys[i] = 0ULL;
            win = i;
        }
        __syncthreads();
        if ((win & 255) == t) {          // only the owner rescans
            kmax = 0ULL;
            #pragma unroll
            for (int j = 0; j < 8; ++j) {
                unsigned long long kk = keys[t + 256 * j];
                if (kk > kmax) kmax = kk;
            }
        }
    }
}

// ---------------------------------------------------------------------------
// Kernel 3: flash-chunked attention, query-split.
// __launch_bounds__(256,3) keeps kreg/vcol in registers (round 7 spill fix).
// (m,l) packed float2 store (round 8 granule-waste fix).
// ---------------------------------------------------------------------------
__global__ __launch_bounds__(256, 3) void attn_kernel(
        const float* __restrict__ Q, const float* __restrict__ K,
        const float* __restrict__ V, const int* __restrict__ topi,
        float2* __restrict__ pml, float* __restrict__ po) {
    __shared__ float  qs[QH][DD];        //  5120 B
    __shared__ float4 e4buf[4][64];      //  4096 B
    __shared__ float  oarea[4][QH][DD];  // 20480 B
    __shared__ float  mlarea[4][QH][2];  //   640 B

    int blk = blockIdx.x;
    int qh  = blk >> 8;                  // 0/1 query half
    int cc2 = blk & 255;
    int c   = cc2 & (NCH - 1);
    int bh  = cc2 >> 3;
    int h = bh & (HH - 1), b = bh >> 3;
    int t = threadIdx.x, lane = t & 63, w = t >> 6;
    int u0 = qh * QH;

    for (int i = t; i < QH * DD; i += 256) {
        int u = i >> 6, d = i & 63;
        int lq = topi[bh * NT + u0 + u];
        qs[u][d] = Q[(((size_t)b * LL + lq) * HH + h) * DD + d];
    }

    int key = c * CH + w * 64 + lane;
    const float4* kr = (const float4*)&K[(((size_t)b * LL + key) * HH + h) * DD];
    float4 kreg[16];
    #pragma unroll
    for (int j = 0; j < 16; ++j) kreg[j] = kr[j];

    float vcol[64];
    const float* vb = &V[(((size_t)b * LL + c * CH + w * 64) * HH + h) * DD + lane];
    #pragma unroll
    for (int j = 0; j < 64; ++j) vcol[j] = vb[(size_t)j * HH * DD];

    __syncthreads();   // qs ready

    for (int uq = 0; uq < QH / 4; ++uq) {
        float o0 = 0, o1 = 0, o2 = 0, o3 = 0;
        float mv0, mv1, mv2, mv3, lv0, lv1, lv2, lv3;
        float4 ev;
        #pragma unroll
        for (int j = 0; j < 4; ++j) {
            int u = uq * 4 + j;
            const float4* q4 = (const float4*)&qs[u][0];
            float s = 0.0f;
            #pragma unroll
            for (int cc = 0; cc < 16; ++cc) {
                float4 qv = q4[cc];
                s += qv.x * kreg[cc].x + qv.y * kreg[cc].y
                   + qv.z * kreg[cc].z + qv.w * kreg[cc].w;
            }
            s *= 0.125f;   // 1/sqrt(64)
            float m = s;
            #pragma unroll
            for (int off = 32; off >= 1; off >>= 1)
                m = fmaxf(m, __shfl_xor(m, off, 64));
            float e = __expf(s - m);
            float ls = e;
            #pragma unroll
            for (int off = 32; off >= 1; off >>= 1)
                ls += __shfl_xor(ls, off, 64);
            if (j == 0) { mv0 = m; lv0 = ls; ev.x = e; }
            if (j == 1) { mv1 = m; lv1 = ls; ev.y = e; }
            if (j == 2) { mv2 = m; lv2 = ls; ev.z = e; }
            if (j == 3) { mv3 = m; lv3 = ls; ev.w = e; }
        }
        e4buf[w][lane] = ev;
        asm volatile("s_waitcnt lgkmcnt(0)" ::: "memory");
        #pragma unroll
        for (int l2 = 0; l2 < 64; ++l2) {      // FULL unroll: vcol static
            float4 e = e4buf[w][l2];
            float  v = vcol[l2];
            o0 += e.x * v; o1 += e.y * v; o2 += e.z * v; o3 += e.w * v;
        }
        oarea[w][uq * 4 + 0][lane] = o0;
        oarea[w][uq * 4 + 1][lane] = o1;
        oarea[w][uq * 4 + 2][lane] = o2;
        oarea[w][uq * 4 + 3][lane] = o3;
        if (lane == 0) {
            mlarea[w][uq * 4 + 0][0] = mv0; mlarea[w][uq * 4 + 0][1] = lv0;
            mlarea[w][uq * 4 + 1][0] = mv1; mlarea[w][uq * 4 + 1][1] = lv1;
            mlarea[w][uq * 4 + 2][0] = mv2; mlarea[w][uq * 4 + 2][1] = lv2;
            mlarea[w][uq * 4 + 3][0] = mv3; mlarea[w][uq * 4 + 3][1] = lv3;
        }
    }
    __syncthreads();

    for (int i = t; i < QH * DD; i += 256) {
        int u = i >> 6, d = i & 63;
        float m0 = mlarea[0][u][0], m1 = mlarea[1][u][0];
        float m2 = mlarea[2][u][0], m3 = mlarea[3][u][0];
        float mb = fmaxf(fmaxf(m0, m1), fmaxf(m2, m3));
        float s0 = __expf(m0 - mb), s1 = __expf(m1 - mb);
        float s2 = __expf(m2 - mb), s3 = __expf(m3 - mb);
        float ob = oarea[0][u][d] * s0 + oarea[1][u][d] * s1
                 + oarea[2][u][d] * s2 + oarea[3][u][d] * s3;
        int gu = u0 + u;
        po[((size_t)(bh * NT + gu) * NCH + c) * DD + d] = ob;
        if (d == 0) {
            float lb = mlarea[0][u][1] * s0 + mlarea[1][u][1] * s1
                     + mlarea[2][u][1] * s2 + mlarea[3][u][1] * s3;
            pml[(bh * NT + gu) * NCH + c] = make_float2(mb, lb);
        }
    }
}

// ---------------------------------------------------------------------------
// Kernel 4: merge chunk partials. One wave per (bh,u), lane = d.
// ---------------------------------------------------------------------------
__global__ __launch_bounds__(256) void merge_kernel(
        const float2* __restrict__ pml, const float* __restrict__ po,
        float* __restrict__ out) {
    int wid  = blockIdx.x * 4 + (threadIdx.x >> 6);
    int lane = threadIdx.x & 63;
    int u  = wid % NT;
    int bh = wid / NT;
    int h = bh & (HH - 1), b = bh >> 3;
    int base = (bh * NT + u) * NCH;

    float m = -INFINITY;
    #pragma unroll
    for (int cc = 0; cc < NCH; ++cc) m = fmaxf(m, pml[base + cc].x);
    float lsum = 0.0f, o = 0.0f;
    #pragma unroll
    for (int cc = 0; cc < NCH; ++cc) {
        float2 ml = pml[base + cc];
        float sc = __expf(ml.x - m);
        lsum += ml.y * sc;
        o    += po[(size_t)(base + cc) * DD + lane] * sc;
    }
    out[(((size_t)b * NT + u) * HH + h) * DD + lane] = o / lsum;
}

extern "C" void kernel_launch(void* const* d_in, const int* in_sizes, int n_in,
                              void* d_out, int out_size, void* d_ws, size_t ws_size,
                              hipStream_t stream) {
    const float* Q   = (const float*)d_in[0];
    const float* K   = (const float*)d_in[1];
    const float* V   = (const float*)d_in[2];
    const int*   idx = (const int*)d_in[3];
    float* out = (float*)d_out;

    char* ws = (char*)d_ws;
    float*  M    = (float*)ws;                        ws += (size_t)BB * HH * LL * sizeof(float);
    int*    topi = (int*)ws;                          ws += (size_t)BB * HH * NT * sizeof(int);
    float2* pml  = (float2*)ws;                       ws += (size_t)BB * HH * NT * NCH * sizeof(float2);
    float*  po   = (float*)ws;                        // 2.62 MB

    hipLaunchKernelGGL(compute_m_kernel, dim3(BB * LL / 4), dim3(256), 0, stream,
                       Q, K, idx, M);
    hipLaunchKernelGGL(topk_kernel, dim3(BB * HH), dim3(256), 0, stream, M, topi);
    hipLaunchKernelGGL(attn_kernel, dim3(2 * BB * HH * NCH), dim3(256), 0, stream,
                       Q, K, V, topi, pml, po);
    hipLaunchKernelGGL(merge_kernel, dim3(BB * HH * NT / 4), dim3(256), 0, stream,
                       pml, po, out);
}